// Round 1
// 578.045 us; speedup vs baseline: 1.2352x; 1.2352x over previous
//
#include <hip/hip_runtime.h>
#include <math.h>

#define NN 50000
#define EE 800000
#define FIN 128
#define NH 5
#define HC 160
#define NG 64
#define CH 128        // fast-path max items per node (deg <= 127)
#define NB 160        // sort blocks
#define EPB 5000      // edges per sort block (NB*EPB == EE)
#define NW 12500      // packed histogram words (4 byte-bins per word)

__device__ __forceinline__ float lrelu(float x, float s) { return x >= 0.f ? x : s * x; }

// ---------------- psum zero + per-graph node counts via binary search (batch sorted)
__global__ void prep_kernel(const int* __restrict__ batch, float* psum, int* gcnt) {
    int i = blockIdx.x * 256 + threadIdx.x;
    if (i < NG * HC) psum[i] = 0.f;
    if (i < NG) {
        int lo = 0, hi = NN;
        while (lo < hi) { int m = (lo + hi) >> 1; if (batch[m] < i) lo = m + 1; else hi = m; }
        int s = lo;
        lo = 0; hi = NN;
        int g1 = i + 1;
        while (lo < hi) { int m = (lo + hi) >> 1; if (batch[m] < g1) lo = m + 1; else hi = m; }
        gcnt[i] = lo - s;
    }
}

// ---------------- per-block LDS histogram of dst (byte-packed, no global atomics)
__global__ __launch_bounds__(256) void hist_kernel(const int* __restrict__ ei,
                                                   unsigned* __restrict__ hist_g) {
    __shared__ unsigned lh[NW];
    int b = blockIdx.x, tid = threadIdx.x;
    for (int w = tid; w < NW; w += 256) lh[w] = 0;
    __syncthreads();
    const int* dstp = ei + EE + b * EPB;
    for (int i = tid; i < EPB; i += 256) {
        int d = dstp[i];
        atomicAdd(&lh[d >> 2], 1u << ((d & 3) * 8));
    }
    __syncthreads();
    unsigned* outp = hist_g + (size_t)b * NW;
    for (int w = tid; w < NW; w += 256) outp[w] = lh[w];
}

// ---------------- column scan over blocks: per-(block,bin) base + total deg
__global__ void sscan_kernel(const unsigned* __restrict__ hist_g,
                             unsigned short* __restrict__ base_g, int* __restrict__ deg) {
    int w = blockIdx.x * 256 + threadIdx.x;
    if (w >= NW) return;
    unsigned r0 = 0, r1 = 0, r2 = 0, r3 = 0;
    for (int b = 0; b < NB; b++) {
        unsigned x = hist_g[(size_t)b * NW + w];
        uint2 st;
        st.x = r0 | (r1 << 16);
        st.y = r2 | (r3 << 16);
        *reinterpret_cast<uint2*>(&base_g[(size_t)b * NN + 4 * w]) = st;
        r0 += x & 0xffu; r1 += (x >> 8) & 0xffu; r2 += (x >> 16) & 0xffu; r3 += (x >> 24) & 0xffu;
    }
    uint4 dv; dv.x = r0; dv.y = r1; dv.z = r2; dv.w = r3;
    *reinterpret_cast<uint4*>(&deg[4 * w]) = dv;
}

// ------------------------------------------------------- 3-phase parallel scan
__global__ void scan1_kernel(const int* __restrict__ deg, int* bsum) {
    __shared__ int ws[4];
    int tid = threadIdx.x, lane = tid & 63, wid = tid >> 6;
    int i = blockIdx.x * 256 + tid;
    int v = (i < NN) ? deg[i] : 0;
    for (int o = 32; o >= 1; o >>= 1) v += __shfl_down(v, o, 64);
    if (lane == 0) ws[wid] = v;
    __syncthreads();
    if (tid == 0) bsum[blockIdx.x] = ws[0] + ws[1] + ws[2] + ws[3];
}

__global__ void scan2_kernel(int* bsum, int* boff) {
    __shared__ int ws[4];
    int tid = threadIdx.x, lane = tid & 63, wid = tid >> 6;
    int v = (tid < 196) ? bsum[tid] : 0;
    int x = v;
    for (int o = 1; o < 64; o <<= 1) {
        int t = __shfl_up(x, o, 64);
        if (lane >= o) x += t;
    }
    if (lane == 63) ws[wid] = x;
    __syncthreads();
    if (tid == 0) {
        int acc = 0;
        for (int w = 0; w < 4; w++) { int t = ws[w]; ws[w] = acc; acc += t; }
    }
    __syncthreads();
    if (tid < 196) boff[tid] = x + ws[wid] - v;
}

__global__ void scan3_kernel(const int* __restrict__ deg, const int* __restrict__ boff,
                             int* off) {
    __shared__ int ws[4];
    int tid = threadIdx.x, lane = tid & 63, wid = tid >> 6;
    int i = blockIdx.x * 256 + tid;
    int v = (i < NN) ? deg[i] : 0;
    int x = v;
    for (int o = 1; o < 64; o <<= 1) {
        int t = __shfl_up(x, o, 64);
        if (lane >= o) x += t;
    }
    if (lane == 63) ws[wid] = x;
    __syncthreads();
    if (tid == 0) {
        int acc = 0;
        for (int w = 0; w < 4; w++) { int t = ws[w]; ws[w] = acc; acc += t; }
    }
    __syncthreads();
    int incl = x + ws[wid] + boff[blockIdx.x];
    if (i < NN) off[i + 1] = incl;
    if (i == 0) off[0] = 0;
}

// ---------------- rank via LDS + write packed edge record (no global atomics)
__global__ __launch_bounds__(256) void scatter_kernel(const int* __restrict__ ei,
                                                      const float* __restrict__ ea,
                                                      const unsigned short* __restrict__ base_g,
                                                      const int* __restrict__ soff,
                                                      uint4* __restrict__ erec) {
    __shared__ unsigned lc[NW];
    int b = blockIdx.x, tid = threadIdx.x;
    for (int w = tid; w < NW; w += 256) lc[w] = 0;
    __syncthreads();
    int e0 = b * EPB;
    const unsigned short* brow = base_g + (size_t)b * NN;
    for (int i = tid; i < EPB; i += 256) {
        int e = e0 + i;
        int d = ei[EE + e];
        int sh = (d & 3) * 8;
        unsigned old = atomicAdd(&lc[d >> 2], 1u << sh);
        int r = (int)((old >> sh) & 0xffu);
        int pos = soff[d] + (int)brow[d] + r;
        uint4 rec;
        rec.x = (unsigned)ei[e];
        rec.y = (unsigned)e;
        rec.z = __float_as_uint(ea[e]);
        rec.w = 0;
        erec[pos] = rec;
    }
}

// -------------------------------------- s[h] = dot(we[h*32: ], ae[h]) per layer
__global__ void preps_kernel(const float* we1, const float* ae1,
                             const float* we2, const float* ae2, float* s_out) {
    int tid = threadIdx.x;
    if (tid < 10) {
        const float* we = (tid < 5) ? we1 : we2;
        const float* ae = (tid < 5) ? ae1 : ae2;
        int h = tid % 5;
        float s = 0.f;
        for (int c = 0; c < 32; c++) s += we[h * 32 + c] * ae[h * 32 + c];
        s_out[tid] = s;
    }
}

// ---------------- h = A @ W  (K = 128 or 160), fused per-(node,head) att dots
template <int K>
__global__ __launch_bounds__(160) void gemm_kernel(const float* __restrict__ A,
                                                   const float* __restrict__ W,
                                                   const float* __restrict__ a_s,
                                                   const float* __restrict__ a_d,
                                                   float* __restrict__ out,
                                                   float* al_s, float* al_d) {
    __shared__ __align__(16) float xs[K][16];
    __shared__ float hs[16][HC + 1];
    int j = threadIdx.x;
    int base = blockIdx.x * 16;
    for (int idx = j; idx < 16 * K; idx += 160) {
        int r = idx / K, k = idx - r * K;
        xs[k][r] = A[(size_t)(base + r) * K + k];
    }
    __syncthreads();
    float acc[16];
#pragma unroll
    for (int r = 0; r < 16; r++) acc[r] = 0.f;
    for (int k = 0; k < K; k++) {
        float wv = W[k * HC + j];
        const float4* row = reinterpret_cast<const float4*>(&xs[k][0]);
        float4 q0 = row[0], q1 = row[1], q2 = row[2], q3 = row[3];
        acc[0] += q0.x * wv;  acc[1] += q0.y * wv;  acc[2] += q0.z * wv;  acc[3] += q0.w * wv;
        acc[4] += q1.x * wv;  acc[5] += q1.y * wv;  acc[6] += q1.z * wv;  acc[7] += q1.w * wv;
        acc[8] += q2.x * wv;  acc[9] += q2.y * wv;  acc[10] += q2.z * wv; acc[11] += q2.w * wv;
        acc[12] += q3.x * wv; acc[13] += q3.y * wv; acc[14] += q3.z * wv; acc[15] += q3.w * wv;
    }
#pragma unroll
    for (int r = 0; r < 16; r++) {
        out[(size_t)(base + r) * HC + j] = acc[r];
        hs[r][j] = acc[r];
    }
    __syncthreads();
    {
        int r = j / 10, rem = j - r * 10;
        int hd = rem >> 1, sd = rem & 1;
        const float* av = sd ? a_d : a_s;
        float s = 0.f;
#pragma unroll
        for (int c = 0; c < 32; c++) s += hs[r][hd * 32 + c] * av[hd * 32 + c];
        float* dst = sd ? al_d : al_s;
        dst[(base + r) * NH + hd] = s;
    }
}

// ------------- per-node (ONE WAVE per node): segment softmax + weighted gather
//               + bias/lrelu/LN.  64-thread blocks: fast/slow branch is
//               block-uniform (one block == one node), barriers degenerate.
__global__ __launch_bounds__(64, 4) void aggregate_kernel(
    const int* __restrict__ soff, const uint4* __restrict__ erec,
    const float* __restrict__ hfeat, const float* __restrict__ al_s,
    const float* __restrict__ al_d, const float* __restrict__ s_e,
    const float* __restrict__ bias, const float* __restrict__ g_ln,
    const float* __restrict__ b_ln,
    float* __restrict__ alpha_out, float* __restrict__ x_out) {
    const int n = blockIdx.x;
    const int lane = threadIdx.x;
    const int s0 = soff[n];
    const int deg = soff[n + 1] - s0;
    const int items = deg + 1;

    __shared__ float w_sh[CH * NH];   // final softmax weights (cross-lane for pass C)
    __shared__ int isrc_sh[CH];

    float adr[NH], ser[NH];
#pragma unroll
    for (int h = 0; h < NH; h++) { adr[h] = al_d[n * NH + h]; ser[h] = s_e[h]; }

    const int c0 = 4 * lane;      // lanes 0..39 own channels c0..c0+3 (float4)
    const int hd = lane >> 3;     // head for those channels (valid for lane<40)
    float4 acc = make_float4(0.f, 0.f, 0.f, 0.f);

    if (items <= CH) {
        // ---- pass A: logits into registers (2 tiles x 5 heads), per-head max, ea sum
        float rw[2][NH];
        float lm[NH];
#pragma unroll
        for (int h = 0; h < NH; h++) lm[h] = -3.0e38f;
        float eas = 0.f;
        int myy[2];
#pragma unroll
        for (int t = 0; t < 2; t++) {
            int i = lane + 64 * t;
            if (i < deg) {
                uint4 rec = erec[s0 + i];
                int src = (int)rec.x;
                float eav = __uint_as_float(rec.z);
                isrc_sh[i] = src;
                myy[t] = (int)rec.y;
                eas += eav;
#pragma unroll
                for (int h = 0; h < NH; h++) {
                    float r = lrelu(al_s[src * NH + h] + adr[h] + eav * ser[h], 0.2f);
                    rw[t][h] = r;
                    lm[h] = fmaxf(lm[h], r);
                }
            }
        }
        // ---- single-wave butterfly: max per head, sum of edge attrs
#pragma unroll
        for (int o = 1; o < 64; o <<= 1) {
#pragma unroll
            for (int h = 0; h < NH; h++) lm[h] = fmaxf(lm[h], __shfl_xor(lm[h], o, 64));
            eas += __shfl_xor(eas, o, 64);
        }
        float emean = eas / fmaxf((float)deg, 1.f);
        float m[NH], rs[NH];
#pragma unroll
        for (int h = 0; h < NH; h++) {
            rs[h] = lrelu(al_s[n * NH + h] + adr[h] + emean * ser[h], 0.2f);
            m[h] = fmaxf(lm[h], rs[h]);
        }
        // ---- pass B: exp in registers + sum
        float ls[NH] = {0.f, 0.f, 0.f, 0.f, 0.f};
#pragma unroll
        for (int t = 0; t < 2; t++) {
            int i = lane + 64 * t;
            if (i < deg) {
#pragma unroll
                for (int h = 0; h < NH; h++) {
                    float w = expf(rw[t][h] - m[h]);
                    rw[t][h] = w;
                    ls[h] += w;
                }
            } else if (i == deg) {          // self-loop owner lane
                isrc_sh[i] = n;
#pragma unroll
                for (int h = 0; h < NH; h++) {
                    float w = expf(rs[h] - m[h]);
                    rw[t][h] = w;
                    ls[h] += w;
                }
            }
        }
#pragma unroll
        for (int o = 1; o < 64; o <<= 1) {
#pragma unroll
            for (int h = 0; h < NH; h++) ls[h] += __shfl_xor(ls[h], o, 64);
        }
        float dinv[NH];
#pragma unroll
        for (int h = 0; h < NH; h++) dinv[h] = 1.f / ls[h];
        // ---- normalize: final weights -> LDS + alpha writeback (y kept in regs)
#pragma unroll
        for (int t = 0; t < 2; t++) {
            int i = lane + 64 * t;
            if (i < items) {
                int opos = (i < deg) ? myy[t] : (EE + n);
#pragma unroll
                for (int h = 0; h < NH; h++) {
                    float w = rw[t][h] * dinv[h];
                    w_sh[i * NH + h] = w;
                    alpha_out[(size_t)opos * NH + h] = w;
                }
            }
        }
        __syncthreads();   // single-wave workgroup: compiles to a fence, orders LDS
        // ---- pass C: float4 channel-parallel weighted gather (lanes 0..39)
        if (lane < 40) {
            for (int i = 0; i < items; i++) {
                float w = w_sh[i * NH + hd];
                const float4 hv = *reinterpret_cast<const float4*>(
                    &hfeat[(size_t)isrc_sh[i] * HC + c0]);
                acc.x += w * hv.x; acc.y += w * hv.y;
                acc.z += w * hv.z; acc.w += w * hv.w;
            }
        }
    } else {
        // ---- slow path (deg >= CH): streaming recompute, no LDS
        float lm[NH];
#pragma unroll
        for (int h = 0; h < NH; h++) lm[h] = -3.0e38f;
        float eas = 0.f;
        for (int i = lane; i < deg; i += 64) {
            uint4 rec = erec[s0 + i];
            int src = (int)rec.x;
            float eav = __uint_as_float(rec.z);
            eas += eav;
#pragma unroll
            for (int h = 0; h < NH; h++) {
                float r = lrelu(al_s[src * NH + h] + adr[h] + eav * ser[h], 0.2f);
                lm[h] = fmaxf(lm[h], r);
            }
        }
#pragma unroll
        for (int o = 1; o < 64; o <<= 1) {
#pragma unroll
            for (int h = 0; h < NH; h++) lm[h] = fmaxf(lm[h], __shfl_xor(lm[h], o, 64));
            eas += __shfl_xor(eas, o, 64);
        }
        float emean = eas / fmaxf((float)deg, 1.f);
        float m[NH], rs[NH];
#pragma unroll
        for (int h = 0; h < NH; h++) {
            rs[h] = lrelu(al_s[n * NH + h] + adr[h] + emean * ser[h], 0.2f);
            m[h] = fmaxf(lm[h], rs[h]);
        }
        float ls[NH] = {0.f, 0.f, 0.f, 0.f, 0.f};
        for (int i = lane; i < items; i += 64) {
            int src; float eav;
            if (i < deg) { uint4 rec = erec[s0 + i]; src = (int)rec.x; eav = __uint_as_float(rec.z); }
            else         { src = n; eav = emean; }
#pragma unroll
            for (int h = 0; h < NH; h++) {
                float r = lrelu(al_s[src * NH + h] + adr[h] + eav * ser[h], 0.2f);
                ls[h] += expf(r - m[h]);
            }
        }
#pragma unroll
        for (int o = 1; o < 64; o <<= 1) {
#pragma unroll
            for (int h = 0; h < NH; h++) ls[h] += __shfl_xor(ls[h], o, 64);
        }
        float dinv[NH];
#pragma unroll
        for (int h = 0; h < NH; h++) dinv[h] = 1.f / ls[h];
        for (int i = lane; i < items; i += 64) {
            int src; float eav; int opos;
            if (i < deg) { uint4 rec = erec[s0 + i]; src = (int)rec.x; eav = __uint_as_float(rec.z); opos = (int)rec.y; }
            else         { src = n; eav = emean; opos = EE + n; }
#pragma unroll
            for (int h = 0; h < NH; h++) {
                float r = lrelu(al_s[src * NH + h] + adr[h] + eav * ser[h], 0.2f);
                alpha_out[(size_t)opos * NH + h] = expf(r - m[h]) * dinv[h];
            }
        }
        if (lane < 40) {
            for (int i = 0; i < items; i++) {
                int src; float eav;
                if (i < deg) { uint4 rec = erec[s0 + i]; src = (int)rec.x; eav = __uint_as_float(rec.z); }
                else         { src = n; eav = emean; }
                float r = lrelu(al_s[src * NH + hd] + adr[hd] + eav * ser[hd], 0.2f);
                float w = expf(r - m[hd]) * dinv[hd];
                const float4 hv = *reinterpret_cast<const float4*>(
                    &hfeat[(size_t)src * HC + c0]);
                acc.x += w * hv.x; acc.y += w * hv.y;
                acc.z += w * hv.z; acc.w += w * hv.w;
            }
        }
    }

    // ---- bias + lrelu + fused LayerNorm across 160 channels (wave butterfly)
    float4 v = make_float4(0.f, 0.f, 0.f, 0.f);
    float p1 = 0.f, p2 = 0.f;
    if (lane < 40) {
        const float4 b4 = *reinterpret_cast<const float4*>(&bias[c0]);
        v.x = lrelu(acc.x + b4.x, 0.01f);
        v.y = lrelu(acc.y + b4.y, 0.01f);
        v.z = lrelu(acc.z + b4.z, 0.01f);
        v.w = lrelu(acc.w + b4.w, 0.01f);
        p1 = v.x + v.y + v.z + v.w;
        p2 = v.x * v.x + v.y * v.y + v.z * v.z + v.w * v.w;
    }
#pragma unroll
    for (int o = 1; o < 64; o <<= 1) {
        p1 += __shfl_xor(p1, o, 64);
        p2 += __shfl_xor(p2, o, 64);
    }
    float mean = p1 * (1.f / (float)HC);
    float var = p2 * (1.f / (float)HC) - mean * mean;
    float rstd = rsqrtf(var + 1e-5f);
    if (lane < 40) {
        const float4 g4 = *reinterpret_cast<const float4*>(&g_ln[c0]);
        const float4 bb = *reinterpret_cast<const float4*>(&b_ln[c0]);
        float4 o4;
        o4.x = (v.x - mean) * rstd * g4.x + bb.x;
        o4.y = (v.y - mean) * rstd * g4.y + bb.y;
        o4.z = (v.z - mean) * rstd * g4.z + bb.z;
        o4.w = (v.w - mean) * rstd * g4.w + bb.w;
        *reinterpret_cast<float4*>(&x_out[(size_t)n * HC + c0]) = o4;
    }
}

// -------- x3 = lrelu(x2 @ mw + mb); fused pooled partial sums (batch sorted)
__global__ __launch_bounds__(160) void gemm3_kernel(const float* A, const float* __restrict__ W,
                                                    const float* __restrict__ bias,
                                                    const int* __restrict__ batch,
                                                    float* x3, float* pooled) {
    __shared__ __align__(16) float xs[HC][16];
    __shared__ int bt[16];
    int j = threadIdx.x;
    int base = blockIdx.x * 16;
    for (int idx = j; idx < 16 * HC; idx += 160) {
        int r = idx / HC, k = idx - r * HC;
        xs[k][r] = A[(size_t)(base + r) * HC + k];
    }
    if (j < 16) bt[j] = batch[base + j];
    __syncthreads();
    float acc[16];
#pragma unroll
    for (int r = 0; r < 16; r++) acc[r] = 0.f;
    for (int k = 0; k < HC; k++) {
        float wv = W[k * HC + j];
        const float4* row = reinterpret_cast<const float4*>(&xs[k][0]);
        float4 q0 = row[0], q1 = row[1], q2 = row[2], q3 = row[3];
        acc[0] += q0.x * wv;  acc[1] += q0.y * wv;  acc[2] += q0.z * wv;  acc[3] += q0.w * wv;
        acc[4] += q1.x * wv;  acc[5] += q1.y * wv;  acc[6] += q1.z * wv;  acc[7] += q1.w * wv;
        acc[8] += q2.x * wv;  acc[9] += q2.y * wv;  acc[10] += q2.z * wv; acc[11] += q2.w * wv;
        acc[12] += q3.x * wv; acc[13] += q3.y * wv; acc[14] += q3.z * wv; acc[15] += q3.w * wv;
    }
    float bj = bias[j];
    float run = 0.f;
    int g = bt[0];
#pragma unroll
    for (int r = 0; r < 16; r++) {
        float vv = lrelu(acc[r] + bj, 0.01f);
        x3[(size_t)(base + r) * HC + j] = vv;
        int gb = bt[r];
        if (gb != g) { atomicAdd(&pooled[g * HC + j], run); run = 0.f; g = gb; }
        run += vv;
    }
    atomicAdd(&pooled[g * HC + j], run);
}

__global__ void pooldiv_kernel(const float* __restrict__ psum, const int* __restrict__ gcnt,
                               float* pooled_out) {
    int i = blockIdx.x * 256 + threadIdx.x;
    if (i < NG * HC) pooled_out[i] = psum[i] / fmaxf((float)gcnt[i / HC], 1.f);
}

// ---------------------------------------------------------------------- launch
extern "C" void kernel_launch(void* const* d_in, const int* in_sizes, int n_in,
                              void* d_out, int out_size, void* d_ws, size_t ws_size,
                              hipStream_t stream) {
    const float* x    = (const float*)d_in[0];
    const int*   ei   = (const int*)d_in[1];
    const float* ea   = (const float*)d_in[2];
    const int*   batch= (const int*)d_in[3];
    const float* w1   = (const float*)d_in[4];
    const float* we1  = (const float*)d_in[5];
    const float* as1  = (const float*)d_in[6];
    const float* ad1  = (const float*)d_in[7];
    const float* ae1  = (const float*)d_in[8];
    const float* b1   = (const float*)d_in[9];
    const float* w2   = (const float*)d_in[10];
    const float* we2  = (const float*)d_in[11];
    const float* as2  = (const float*)d_in[12];
    const float* ad2  = (const float*)d_in[13];
    const float* ae2  = (const float*)d_in[14];
    const float* b2   = (const float*)d_in[15];
    const float* ln1g = (const float*)d_in[16];
    const float* ln1b = (const float*)d_in[17];
    const float* ln2g = (const float*)d_in[18];
    const float* ln2b = (const float*)d_in[19];
    const float* mw   = (const float*)d_in[20];
    const float* mb   = (const float*)d_in[21];

    float* out = (float*)d_out;
    float* x12 = out;                                 // x1/x2 scratch in x3 region
    float* pooled_out = out + (size_t)NN * HC;
    float* a1 = pooled_out + NG * HC;
    float* a2 = a1 + (size_t)(EE + NN) * NH;

    char* wp = (char*)d_ws;
    auto alloc = [&](size_t bytes) {
        void* p = (void*)wp;
        wp += (bytes + 255) & ~(size_t)255;
        return p;
    };
    float* hbuf  = (float*)alloc((size_t)NN * HC * 4);   // 32 MB
    // hist_g/base_g overlay hbuf (dead before gemm1 writes hbuf)
    unsigned*       hist_g = (unsigned*)hbuf;                       // 8 MB
    unsigned short* base_g = (unsigned short*)((char*)hbuf + 8 * 1024 * 1024); // 16 MB
    uint4* erec  = (uint4*)alloc((size_t)EE * 16);       // 12.8 MB
    float* als   = (float*)alloc((size_t)NN * NH * 4);
    float* ald   = (float*)alloc((size_t)NN * NH * 4);
    int*   deg   = (int*)alloc((size_t)NN * 4);
    int*   soff  = (int*)alloc((size_t)(NN + 1) * 4);
    float* sbuf  = (float*)alloc(64);
    float* psum  = (float*)alloc((size_t)NG * HC * 4);
    int*   gcnt  = (int*)alloc((size_t)NG * 4);
    int*   bsum  = (int*)alloc(256 * 4);
    int*   boff  = (int*)alloc(256 * 4);

    prep_kernel<<<40, 256, 0, stream>>>(batch, psum, gcnt);
    hist_kernel<<<NB, 256, 0, stream>>>(ei, hist_g);
    sscan_kernel<<<49, 256, 0, stream>>>(hist_g, base_g, deg);
    scan1_kernel<<<196, 256, 0, stream>>>(deg, bsum);
    scan2_kernel<<<1, 256, 0, stream>>>(bsum, boff);
    scan3_kernel<<<196, 256, 0, stream>>>(deg, boff, soff);
    scatter_kernel<<<NB, 256, 0, stream>>>(ei, ea, base_g, soff, erec);
    preps_kernel<<<1, 64, 0, stream>>>(we1, ae1, we2, ae2, sbuf);

    gemm_kernel<128><<<3125, 160, 0, stream>>>(x, w1, as1, ad1, hbuf, als, ald);
    aggregate_kernel<<<NN, 64, 0, stream>>>(soff, erec, hbuf, als, ald,
                                            sbuf, b1, ln1g, ln1b, a1, x12);

    gemm_kernel<160><<<3125, 160, 0, stream>>>(x12, w2, as2, ad2, hbuf, als, ald);
    aggregate_kernel<<<NN, 64, 0, stream>>>(soff, erec, hbuf, als, ald,
                                            sbuf + 5, b2, ln2g, ln2b, a2, x12);

    gemm3_kernel<<<3125, 160, 0, stream>>>(x12, mw, mb, batch, out, psum);
    pooldiv_kernel<<<40, 256, 0, stream>>>(psum, gcnt, pooled_out);
}